// Round 18
// baseline (250.258 us; speedup 1.0000x reference)
//
#include <hip/hip_runtime.h>
#include <hip/hip_fp16.h>
#include <cstdint>
#include <cstddef>

// Problem constants: B=256, C=1, NMAX=256 -> N=65536 nodes, E=N*16=1048576,
// EMB=HID=128, decode K = NMAX = 256. Bucket b (= dst>>8) == graph b.
#define NN   65536
#define NE   1048576
#define FD   128
#define KDEC 256
#define NGRAPH 256
#define DUMMY_SRC 65536u         // zero row index (row NN of each slice)
#define EPB  4096                // edges per binning block
#define BCAP 4608                // per-bucket record capacity (mean 4096 + 8 sigma)
#define BCAPP 6656               // per-bucket PADDED ec window (BCAP + 8*256)
#define SLROW (NN + 1)           // rows per slice (incl. zero row)

typedef __attribute__((ext_vector_type(8))) short s16x8;
typedef __attribute__((ext_vector_type(4))) float f32x4;

__device__ __forceinline__ ushort f2bf(float x) {
  uint u = __float_as_uint(x);
  uint r = (u + 0x7fffu + ((u >> 16) & 1u)) >> 16;  // RNE
  return (ushort)r;
}
__device__ __forceinline__ float bf2f(ushort h) {
  return __uint_as_float(((uint)h) << 16);
}

// W split helper (fragment-major):
// dst(k,c) = ((k/32)*8 + c/16)*512 + ((c&15) + 16*((k&31)>>3))*8 + (k&7)
__device__ __forceinline__ void wsplit(float w, int k, int c,
                                       ushort* __restrict__ H,
                                       ushort* __restrict__ L) {
  ushort h = f2bf(w);
  size_t dst = ((size_t)((k >> 5) * 8 + (c >> 4)) * 64 +
                (size_t)((c & 15) + 16 * ((k & 31) >> 3))) * 8 + (k & 7);
  H[dst] = h;
  L[dst] = f2bf(w - bf2f(h));
}

// ---------------- histbin: edge binning + ALL weight prep (parallel roles) ----

__global__ __launch_bounds__(1024) void k_histbin(const int* __restrict__ edges,
                                                  uint* __restrict__ binbuf,
                                                  int* __restrict__ gbin,
                                                  const float* __restrict__ Wdec,
                                                  const float* __restrict__ Wc1,
                                                  const float* __restrict__ bdec,
                                                  float* __restrict__ bfused,
                                                  ushort* __restrict__ wfh,
                                                  ushort* __restrict__ wfl,
                                                  const float* __restrict__ Wc2,
                                                  ushort* __restrict__ w2h,
                                                  ushort* __restrict__ w2l) {
  const int b = blockIdx.x, t = threadIdx.x;
  if (b >= 256) {
    if (b < 288) {
      int i = (b - 256) * 1024 + t;  // 0..32767
      int k = i >> 7, c = i & 127;
      float acc = 0.f;
#pragma unroll 8
      for (int j = 0; j < 128; j++) acc = fmaf(Wdec[k * FD + j], Wc1[j * FD + c], acc);
      wsplit(acc, k, c, wfh, wfl);
      if (b == 256 && t < 128) {
        float ba = 0.f;
        for (int j = 0; j < 128; j++) ba = fmaf(bdec[j], Wc1[j * FD + t], ba);
        bfused[t] = ba;
      }
    } else {
      int i = (b - 288) * 1024 + t;  // 0..16383
      wsplit(Wc2[i], i >> 7, i & 127, w2h, w2l);
    }
    return;
  }
  __shared__ int lcnt[256];
  __shared__ int lsum[256];   // inclusive prefix of lcnt
  __shared__ int gbase[256];
  __shared__ uint sorted[EPB];

  if (t < 256) lcnt[t] = 0;
  __syncthreads();

  uint rec[4];
  ushort bkt[4], lidx[4];
#pragma unroll
  for (int r = 0; r < 4; r++) {
    int i = b * EPB + r * 1024 + t;
    int2 e = ((const int2*)edges)[i];
    int bucket = e.y >> 8;
    int li = atomicAdd(&lcnt[bucket], 1);
    rec[r] = ((uint)bucket << 24) | ((uint)(e.y & 255) << 16) | (uint)e.x;
    bkt[r] = (ushort)bucket;
    lidx[r] = (ushort)li;
  }
  __syncthreads();

  if (t < 256) lsum[t] = lcnt[t];
  __syncthreads();
  for (int off = 1; off < 256; off <<= 1) {
    int v = 0;
    if (t < 256 && t >= off) v = lsum[t - off];
    __syncthreads();
    if (t < 256) lsum[t] += v;
    __syncthreads();
  }
  if (t < 256) gbase[t] = atomicAdd(&gbin[t], lcnt[t]);
  __syncthreads();

#pragma unroll
  for (int r = 0; r < 4; r++) {
    int B = bkt[r];
    sorted[lsum[B] - lcnt[B] + lidx[r]] = rec[r];
  }
  __syncthreads();

  for (int s = t; s < EPB; s += 1024) {
    uint v = sorted[s];
    int B = v >> 24;
    int ex = lsum[B] - lcnt[B];
    binbuf[B * BCAP + gbase[B] + (s - ex)] = v & 0xFFFFFFu;  // (dlow<<16)|src
  }
}

// ---------------- misc: bucket-local CSR build (pad-to-8), zero rows ----------

__global__ __launch_bounds__(256) void k_misc(const uint* __restrict__ binbuf,
                                              const int* __restrict__ gbin,
                                              int* __restrict__ hist,
                                              int* __restrict__ offs,
                                              float* __restrict__ dinv,
                                              uint* __restrict__ ec,
                                              ushort* __restrict__ h16s) {
  __shared__ int lc[256];
  __shared__ int s[256];
  __shared__ int sofs[256];
  __shared__ int cnt2[256];
  const int b = blockIdx.x, t = threadIdx.x;
  lc[t] = 0;
  cnt2[t] = 0;
  __syncthreads();
  const int m = gbin[b];
  const uint* bp_ = binbuf + (size_t)b * BCAP;
  for (int i = t; i < m; i += 256)
    atomicAdd(&lc[bp_[i] >> 16], 1);
  __syncthreads();
  const int v = lc[t];
  const int vp = (v + 7) & ~7;  // pad to 8 (agg uses 8-way edge parity)
  s[t] = vp;
  __syncthreads();
  for (int off = 1; off < 256; off <<= 1) {
    int add = (t >= off) ? s[t - off] : 0;
    __syncthreads();
    s[t] += add;
    __syncthreads();
  }
  const int of = b * BCAPP + s[t] - vp;  // absolute padded exclusive offset
  offs[b * 256 + t] = of;
  hist[b * 256 + t] = v;
  dinv[b * 256 + t] = rsqrtf((float)(v + 1));
  sofs[t] = of;
  __syncthreads();

  for (int i = t; i < m; i += 256) {
    uint rec = bp_[i];
    int dlow = rec >> 16;
    int pos = sofs[dlow] + atomicAdd(&cnt2[dlow], 1);
    ec[pos] = rec & 0xFFFFu;
  }
  __syncthreads();
  int base = sofs[t];
  for (int j = v; j < vp; j++) ec[base + j] = DUMMY_SRC;
  // zero rows (row NN of each of the 4 slices): 4*32 = 128 ushorts
  if (b == 0 && t < 128) {
    int sl = t >> 5, d = t & 31;
    h16s[((size_t)sl * SLROW + NN) * 32 + d] = 0;
  }
}

// ---------------- split-bf16 MFMA GEMM, LDS-B dbuf + 2-deep A prefetch ----------
// Output: SLICED bf16 table [4][SLROW][32], dst = (col>>5)*SLROW*32 + row*32 +
// (col&31), row-scaled by scale[]. AMODE 0: fp32 A 3-pass. AMODE 1: bf16 A 2-pass.

#define GEMM_ISSUE_A(S, AR, AB)                                           \
  {                                                                       \
    _Pragma("unroll")                                                     \
    for (int mb = 0; mb < 2; mb++) {                                      \
      size_t base_ = (size_t)(r0 + mb * 16 + lr) * K + (S) * 32 + kg * 8; \
      if (AMODE == 0) {                                                   \
        const float* xp_ = (const float*)A0 + base_;                      \
        AR[mb * 2] = *(const f32x4*)xp_;                                  \
        AR[mb * 2 + 1] = *(const f32x4*)(xp_ + 4);                        \
      } else {                                                            \
        AB[mb] = *(const s16x8*)((const ushort*)A0 + base_);              \
      }                                                                   \
    }                                                                     \
  }

#define GEMM_STEP(S, AR, AB)                                              \
  {                                                                       \
    s16x8 ah[2], al[2];                                                   \
    if (AMODE == 0) {                                                     \
      _Pragma("unroll")                                                   \
      for (int mb = 0; mb < 2; mb++) {                                    \
        float xv[8] = {AR[mb*2].x, AR[mb*2].y, AR[mb*2].z, AR[mb*2].w,    \
                       AR[mb*2+1].x, AR[mb*2+1].y, AR[mb*2+1].z,          \
                       AR[mb*2+1].w};                                     \
        union { ushort u[8]; s16x8 v; } H_, L_;                           \
        _Pragma("unroll")                                                 \
        for (int e = 0; e < 8; e++) {                                     \
          ushort h_ = f2bf(xv[e]);                                        \
          H_.u[e] = h_;                                                   \
          L_.u[e] = f2bf(xv[e] - bf2f(h_));                               \
        }                                                                 \
        ah[mb] = H_.v;                                                    \
        al[mb] = L_.v;                                                    \
      }                                                                   \
    } else {                                                              \
      ah[0] = AB[0];                                                      \
      ah[1] = AB[1];                                                      \
      al[0] = AB[0];  /* unused in AMODE 1 */                             \
      al[1] = AB[1];                                                      \
    }                                                                     \
    if ((S) + 2 < nks) GEMM_ISSUE_A((S) + 2, AR, AB);                     \
    const bool more_ = ((S) + 1 < nks);                                   \
    if (more_) issueB((S) + 1);                                           \
    _Pragma("unroll")                                                     \
    for (int nb = 0; nb < 8; nb++) {                                      \
      s16x8 bh = *(const s16x8*)&Bs[buf][nb * 512 + l * 8];               \
      s16x8 bl = *(const s16x8*)&Bs[buf][4096 + nb * 512 + l * 8];        \
      _Pragma("unroll")                                                   \
      for (int mb = 0; mb < 2; mb++) {                                    \
        acc[mb][nb] = __builtin_amdgcn_mfma_f32_16x16x32_bf16(            \
            ah[mb], bh, acc[mb][nb], 0, 0, 0);                            \
        acc[mb][nb] = __builtin_amdgcn_mfma_f32_16x16x32_bf16(            \
            ah[mb], bl, acc[mb][nb], 0, 0, 0);                            \
        if (AMODE == 0)                                                   \
          acc[mb][nb] = __builtin_amdgcn_mfma_f32_16x16x32_bf16(          \
              al[mb], bh, acc[mb][nb], 0, 0, 0);                          \
      }                                                                   \
    }                                                                     \
    if (more_) {                                                          \
      writeB(buf ^ 1);                                                    \
      __syncthreads();                                                    \
      buf ^= 1;                                                           \
    }                                                                     \
  }

template <int AMODE>
__global__ __launch_bounds__(256) void k_gemm(const void* __restrict__ A0,
                                              const ushort* __restrict__ Whi,
                                              const ushort* __restrict__ Wlo,
                                              const float* __restrict__ bias,
                                              const float* __restrict__ scale,
                                              ushort* __restrict__ Y, int K) {
  __shared__ ushort Bs[2][8192];  // [buf][hi 4096 | lo 4096] = 32 KB
  const int t = threadIdx.x;
  const int w = t >> 6;
  const int l = t & 63;
  const int lr = l & 15;
  const int kg = l >> 4;
  const int r0 = blockIdx.x * 128 + w * 32;
  const int nks = K >> 5;  // 8 (decode) or 4 — always even

  f32x4 acc[2][8];
#pragma unroll
  for (int mb = 0; mb < 2; mb++)
#pragma unroll
    for (int nb = 0; nb < 8; nb++) acc[mb][nb] = (f32x4)0.f;

  // statically-named 2-deep A prefetch sets (rule #20)
  f32x4 arA[4], arB[4];
  s16x8 abA[2], abB[2];
  s16x8 bh0, bh1, bl0, bl1;

  auto issueB = [&](int s) {
    const ushort* ph = Whi + (size_t)s * 4096 + t * 16;
    const ushort* pl = Wlo + (size_t)s * 4096 + t * 16;
    bh0 = *(const s16x8*)ph;
    bh1 = *(const s16x8*)(ph + 8);
    bl0 = *(const s16x8*)pl;
    bl1 = *(const s16x8*)(pl + 8);
  };
  auto writeB = [&](int buf) {
    *(s16x8*)&Bs[buf][t * 16] = bh0;
    *(s16x8*)&Bs[buf][t * 16 + 8] = bh1;
    *(s16x8*)&Bs[buf][4096 + t * 16] = bl0;
    *(s16x8*)&Bs[buf][4096 + t * 16 + 8] = bl1;
  };

  GEMM_ISSUE_A(0, arA, abA);
  issueB(0);
  writeB(0);
  GEMM_ISSUE_A(1, arB, abB);  // nks >= 2 always
  __syncthreads();

  int buf = 0;
  for (int s = 0; s < nks; s += 2) {
    GEMM_STEP(s, arA, abA);
    GEMM_STEP(s + 1, arB, abB);
  }

  float dvr[2][4];
#pragma unroll
  for (int mb = 0; mb < 2; mb++)
#pragma unroll
    for (int r = 0; r < 4; r++)
      dvr[mb][r] = scale ? scale[r0 + mb * 16 + kg * 4 + r] : 1.f;

#pragma unroll
  for (int nb = 0; nb < 8; nb++) {
    int col = nb * 16 + lr;
    float bv = bias ? bias[col] : 0.f;
    size_t sbase = (size_t)(col >> 5) * SLROW * 32 + (col & 31);
#pragma unroll
    for (int mb = 0; mb < 2; mb++)
#pragma unroll
      for (int r = 0; r < 4; r++) {
        size_t row = (size_t)(r0 + mb * 16 + kg * 4 + r);
        Y[sbase + row * 32] = f2bf((acc[mb][nb][r] + bv) * dvr[mb][r]);
      }
  }
}

// ---------------- GCN aggregation: XCD-pinned sliced table, wave-per-node-slice
// Table [4][SLROW][32] bf16 (t = dinv*h); slice = bid&3 -> pinned to XCDs
// {s, s+4} (4 MB/slice resident in L2 -> kills the ~99MB table re-fetch).
// Wave = 1 node x 1 slice: lane l = (parity p=l>>3, dim-quad q=l&7).
// 8 edges/iter (one per parity group, full 64B row per group), counts padded
// to 8 -> uniform loop, zero divergence. Reduce = 3 shfl_xor (8/16/32).
// EMIT=0: write x1 row-major (full 64B line per node-slice).
// EMIT=1: block-local max (4 nodes) -> global atomicMax into pooled.

template <int EMIT>
__global__ __launch_bounds__(256) void k_agg(const ushort* __restrict__ h16s,
                                             const uint* __restrict__ ec,
                                             const int* __restrict__ offs,
                                             const int* __restrict__ hist,
                                             const float* __restrict__ dinv,
                                             const float* __restrict__ bias,
                                             ushort* __restrict__ x1,
                                             float* __restrict__ pooled) {
  __shared__ int pmax[32];
  const int bid = blockIdx.x, t = threadIdx.x;
  const int s = bid & 3;
  const int n = (bid >> 2) * 4 + (t >> 6);
  const int l = t & 63;
  const int p = l >> 3;        // edge parity 0..7
  const int q = l & 7;         // dim quad: dims q*4..q*4+3 of the slice
  if (EMIT == 1) {
    if (t < 32) pmax[t] = 0;
    __syncthreads();
  }

  const ushort* tab = h16s + (size_t)s * SLROW * 32 + q * 4;
  const int cnt_p = (hist[n] + 7) & ~7;
  const uint* ep = ec + offs[n];

  float a0 = 0.f, a1 = 0.f, a2 = 0.f, a3 = 0.f;
  float b0 = 0.f, b1 = 0.f, b2 = 0.f, b3 = 0.f;
  int i = p;
  for (; i + 8 < cnt_p; i += 16) {
    uint s0 = ep[i];
    uint s1 = ep[i + 8];
    ushort4 v0 = *(const ushort4*)(tab + (size_t)s0 * 32);
    ushort4 v1 = *(const ushort4*)(tab + (size_t)s1 * 32);
    a0 += bf2f(v0.x); a1 += bf2f(v0.y); a2 += bf2f(v0.z); a3 += bf2f(v0.w);
    b0 += bf2f(v1.x); b1 += bf2f(v1.y); b2 += bf2f(v1.z); b3 += bf2f(v1.w);
  }
  if (i < cnt_p) {
    uint s0 = ep[i];
    ushort4 v0 = *(const ushort4*)(tab + (size_t)s0 * 32);
    a0 += bf2f(v0.x); a1 += bf2f(v0.y); a2 += bf2f(v0.z); a3 += bf2f(v0.w);
  }
  a0 += b0; a1 += b1; a2 += b2; a3 += b3;
  // sum over the 8 parity groups (lanes with same q)
#pragma unroll
  for (int m = 8; m <= 32; m <<= 1) {
    a0 += __shfl_xor(a0, m);
    a1 += __shfl_xor(a1, m);
    a2 += __shfl_xor(a2, m);
    a3 += __shfl_xor(a3, m);
  }

  if (p == 0) {  // lanes 0..7 hold the full slice sum for their dim quad
    float dv = dinv[n];
    ushort4 vs = *(const ushort4*)(tab + (size_t)n * 32);  // t[n]
    float4 bb = *(const float4*)(bias + s * 32 + q * 4);
    float o0 = fmaxf(fmaf(dv, a0 + bf2f(vs.x), bb.x), 0.f);
    float o1 = fmaxf(fmaf(dv, a1 + bf2f(vs.y), bb.y), 0.f);
    float o2 = fmaxf(fmaf(dv, a2 + bf2f(vs.z), bb.z), 0.f);
    float o3 = fmaxf(fmaf(dv, a3 + bf2f(vs.w), bb.w), 0.f);
    if (EMIT == 0) {
      ushort4 hi;
      hi.x = f2bf(o0);
      hi.y = f2bf(o1);
      hi.z = f2bf(o2);
      hi.w = f2bf(o3);
      *(ushort4*)(x1 + (size_t)n * FD + s * 32 + q * 4) = hi;
    } else {
      // relu>=0: int-compare == float-compare for non-negative floats
      atomicMax(&pmax[q * 4 + 0], __float_as_int(o0));
      atomicMax(&pmax[q * 4 + 1], __float_as_int(o1));
      atomicMax(&pmax[q * 4 + 2], __float_as_int(o2));
      atomicMax(&pmax[q * 4 + 3], __float_as_int(o3));
    }
  }
  if (EMIT == 1) {
    __syncthreads();
    if (t < 32) {
      int gr = bid >> 8;  // block's 4 nodes all in graph (bid>>2)*4/256
      atomicMax((int*)pooled + gr * FD + s * 32 + t, pmax[t]);
    }
  }
}

// ---------------- MLP head ----------------

__global__ __launch_bounds__(128) void k_mlp(const float* __restrict__ pooled,
                                             const float* __restrict__ Wp1,
                                             const float* __restrict__ bp1,
                                             const float* __restrict__ Wp2,
                                             const float* __restrict__ bp2,
                                             float* __restrict__ out) {
  __shared__ float row[128];
  __shared__ float red[128];
  int g = blockIdx.x, t = threadIdx.x;
  row[t] = pooled[g * FD + t];
  __syncthreads();
  float acc = bp1[t];
#pragma unroll 8
  for (int k = 0; k < 128; k++) acc = fmaf(row[k], Wp1[k * FD + t], acc);
  acc = fmaxf(acc, 0.f);
  red[t] = acc * Wp2[t];
  __syncthreads();
  for (int st = 64; st > 0; st >>= 1) {
    if (t < st) red[t] += red[t + st];
    __syncthreads();
  }
  if (t == 0) out[g] = red[0] + bp2[0];
}

// ---------------- launch ----------------

extern "C" void kernel_launch(void* const* d_in, const int* in_sizes, int n_in,
                              void* d_out, int out_size, void* d_ws, size_t ws_size,
                              hipStream_t stream) {
  (void)in_sizes; (void)n_in; (void)out_size; (void)ws_size;

  const float* adj  = (const float*)d_in[0];
  const int*   edges= (const int*)d_in[1];
  const float* Wdec = (const float*)d_in[3];
  const float* bdec = (const float*)d_in[4];
  const float* Wc1  = (const float*)d_in[5];
  const float* bc1  = (const float*)d_in[6];
  const float* Wc2  = (const float*)d_in[7];
  const float* bc2  = (const float*)d_in[8];
  const float* Wp1  = (const float*)d_in[9];
  const float* bp1  = (const float*)d_in[10];
  const float* Wp2  = (const float*)d_in[11];
  const float* bp2  = (const float*)d_in[12];
  float* out = (float*)d_out;

  char* ws = (char*)d_ws;
  size_t off = 0;
  auto alloc = [&](size_t bytes) -> void* {
    void* p = ws + off;
    off += (bytes + 255) & ~(size_t)255;
    return p;
  };
  ushort* h16s = (ushort*)alloc((size_t)4 * SLROW * 32 * 2);  // sliced table ~16.8MB
  ushort* x1   = (ushort*)alloc((size_t)NN * FD * 2);         // row-major bf16
  // pooled | gbin contiguous -> single memset
  float*  pooled = (float*)alloc((size_t)NGRAPH * FD * 4);
  int*    gbin = (int*)alloc(256 * 4);
  int*    hist = (int*)alloc((size_t)NN * 4);
  int*    offs = (int*)alloc((size_t)NN * 4);
  uint*   ec   = (uint*)alloc((size_t)256 * BCAPP * 4);   // 6.8 MB fixed windows
  uint*   binbuf = (uint*)alloc((size_t)256 * BCAP * 4);  // 4.7 MB bucket bins
  float*  dinv = (float*)alloc((size_t)NN * 4);
  float*  bfused = (float*)alloc(FD * 4);
  ushort* wfh = (ushort*)alloc((size_t)KDEC * FD * 2);
  ushort* wfl = (ushort*)alloc((size_t)KDEC * FD * 2);
  ushort* w2h = (ushort*)alloc((size_t)FD * FD * 2);
  ushort* w2l = (ushort*)alloc((size_t)FD * FD * 2);

  hipMemsetAsync(pooled, 0, (size_t)NGRAPH * FD * 4 + 256 * 4, stream);

  // binning + Wfused compute&split + Wc2 split (parallel block roles)
  k_histbin<<<304, 1024, 0, stream>>>(edges, binbuf, gbin, Wdec, Wc1, bdec,
                                      bfused, wfh, wfl, Wc2, w2h, w2l);
  // bucket-local CSR (pad-to-8) + zero rows of the sliced table
  k_misc<<<256, 256, 0, stream>>>(binbuf, gbin, hist, offs, dinv, ec, h16s);

  // t1 = dinv * (adj @ Wfused + bfused) -> sliced bf16 table
  k_gemm<0><<<NN / 128, 256, 0, stream>>>(adj, wfh, wfl, bfused, dinv, h16s, KDEC);

  // x1 = relu(dinv*(sum t1 + t1_self) + bc1) -> row-major bf16 plane
  k_agg<0><<<NN, 256, 0, stream>>>(h16s, ec, offs, hist, dinv, bc1, x1, nullptr);

  // t2 = dinv * (x1 @ Wc2) -> sliced bf16 table
  k_gemm<1><<<NN / 128, 256, 0, stream>>>(x1, w2h, w2l, nullptr, dinv, h16s, FD);

  // pooled = segmax(relu(dinv*(sum t2 + t2_self) + bc2)) fused
  k_agg<1><<<NN, 256, 0, stream>>>(h16s, ec, offs, hist, dinv, bc2, nullptr, pooled);

  // MLP head
  k_mlp<<<NGRAPH, 128, 0, stream>>>(pooled, Wp1, bp1, Wp2, bp2, out);
}

// Round 19
// 166.950 us; speedup vs baseline: 1.4990x; 1.4990x over previous
//
#include <hip/hip_runtime.h>
#include <hip/hip_fp16.h>
#include <cstdint>
#include <cstddef>

// Problem constants: B=256, C=1, NMAX=256 -> N=65536 nodes, E=N*16=1048576,
// EMB=HID=128, decode K = NMAX = 256. Bucket b (= dst>>8) == graph b.
#define NN   65536
#define NE   1048576
#define FD   128
#define KDEC 256
#define NGRAPH 256
#define DUMMY_SRC 65536u         // zero row index
#define EPB  4096                // edges per binning block
#define BCAP 4608                // per-bucket record capacity (mean 4096 + 8 sigma)
#define BCAPP 8448               // per-bucket PADDED ec window (BCAP + 15*256)

typedef __attribute__((ext_vector_type(8))) short s16x8;
typedef __attribute__((ext_vector_type(4))) float f32x4;

__device__ __forceinline__ ushort f2bf(float x) {
  uint u = __float_as_uint(x);
  uint r = (u + 0x7fffu + ((u >> 16) & 1u)) >> 16;  // RNE
  return (ushort)r;
}
__device__ __forceinline__ float bf2f(ushort h) {
  return __uint_as_float(((uint)h) << 16);
}

// W split helper (fragment-major):
// dst(k,c) = ((k/32)*8 + c/16)*512 + ((c&15) + 16*((k&31)>>3))*8 + (k&7)
__device__ __forceinline__ void wsplit(float w, int k, int c,
                                       ushort* __restrict__ H,
                                       ushort* __restrict__ L) {
  ushort h = f2bf(w);
  size_t dst = ((size_t)((k >> 5) * 8 + (c >> 4)) * 64 +
                (size_t)((c & 15) + 16 * ((k & 31) >> 3))) * 8 + (k & 7);
  H[dst] = h;
  L[dst] = f2bf(w - bf2f(h));
}

// ---------------- histbin: edge binning + ALL weight prep (parallel roles) ----

__global__ __launch_bounds__(1024) void k_histbin(const int* __restrict__ edges,
                                                  uint* __restrict__ binbuf,
                                                  int* __restrict__ gbin,
                                                  const float* __restrict__ Wdec,
                                                  const float* __restrict__ Wc1,
                                                  const float* __restrict__ bdec,
                                                  float* __restrict__ bfused,
                                                  ushort* __restrict__ wfh,
                                                  ushort* __restrict__ wfl,
                                                  const float* __restrict__ Wc2,
                                                  ushort* __restrict__ w2h,
                                                  ushort* __restrict__ w2l) {
  const int b = blockIdx.x, t = threadIdx.x;
  if (b >= 256) {
    if (b < 288) {
      int i = (b - 256) * 1024 + t;  // 0..32767
      int k = i >> 7, c = i & 127;
      float acc = 0.f;
#pragma unroll 8
      for (int j = 0; j < 128; j++) acc = fmaf(Wdec[k * FD + j], Wc1[j * FD + c], acc);
      wsplit(acc, k, c, wfh, wfl);
      if (b == 256 && t < 128) {
        float ba = 0.f;
        for (int j = 0; j < 128; j++) ba = fmaf(bdec[j], Wc1[j * FD + t], ba);
        bfused[t] = ba;
      }
    } else {
      int i = (b - 288) * 1024 + t;  // 0..16383
      wsplit(Wc2[i], i >> 7, i & 127, w2h, w2l);
    }
    return;
  }
  __shared__ int lcnt[256];
  __shared__ int lsum[256];   // inclusive prefix of lcnt
  __shared__ int gbase[256];
  __shared__ uint sorted[EPB];

  if (t < 256) lcnt[t] = 0;
  __syncthreads();

  uint rec[4];
  ushort bkt[4], lidx[4];
#pragma unroll
  for (int r = 0; r < 4; r++) {
    int i = b * EPB + r * 1024 + t;
    int2 e = ((const int2*)edges)[i];
    int bucket = e.y >> 8;
    int li = atomicAdd(&lcnt[bucket], 1);
    rec[r] = ((uint)bucket << 24) | ((uint)(e.y & 255) << 16) | (uint)e.x;
    bkt[r] = (ushort)bucket;
    lidx[r] = (ushort)li;
  }
  __syncthreads();

  if (t < 256) lsum[t] = lcnt[t];
  __syncthreads();
  for (int off = 1; off < 256; off <<= 1) {
    int v = 0;
    if (t < 256 && t >= off) v = lsum[t - off];
    __syncthreads();
    if (t < 256) lsum[t] += v;
    __syncthreads();
  }
  if (t < 256) gbase[t] = atomicAdd(&gbin[t], lcnt[t]);
  __syncthreads();

#pragma unroll
  for (int r = 0; r < 4; r++) {
    int B = bkt[r];
    sorted[lsum[B] - lcnt[B] + lidx[r]] = rec[r];
  }
  __syncthreads();

  for (int s = t; s < EPB; s += 1024) {
    uint v = sorted[s];
    int B = v >> 24;
    int ex = lsum[B] - lcnt[B];
    binbuf[B * BCAP + gbase[B] + (s - ex)] = v & 0xFFFFFFu;  // (dlow<<16)|src
  }
}

// ---------------- misc: bucket-local CSR build, one pass, no global scan -------

__global__ __launch_bounds__(256) void k_misc(const uint* __restrict__ binbuf,
                                              const int* __restrict__ gbin,
                                              int* __restrict__ hist,
                                              int* __restrict__ offs,
                                              float* __restrict__ dinv,
                                              uint* __restrict__ ec) {
  __shared__ int lc[256];
  __shared__ int s[256];
  __shared__ int sofs[256];
  __shared__ int cnt2[256];
  const int b = blockIdx.x, t = threadIdx.x;
  lc[t] = 0;
  cnt2[t] = 0;
  __syncthreads();
  const int m = gbin[b];
  const uint* bp_ = binbuf + (size_t)b * BCAP;
  for (int i = t; i < m; i += 256)
    atomicAdd(&lc[bp_[i] >> 16], 1);
  __syncthreads();
  const int v = lc[t];
  const int vp = (v + 15) & ~15;
  s[t] = vp;
  __syncthreads();
  for (int off = 1; off < 256; off <<= 1) {
    int add = (t >= off) ? s[t - off] : 0;
    __syncthreads();
    s[t] += add;
    __syncthreads();
  }
  const int of = b * BCAPP + s[t] - vp;  // absolute padded exclusive offset
  offs[b * 256 + t] = of;
  hist[b * 256 + t] = v;
  dinv[b * 256 + t] = rsqrtf((float)(v + 1));
  sofs[t] = of;
  __syncthreads();

  for (int i = t; i < m; i += 256) {
    uint rec = bp_[i];
    int dlow = rec >> 16;
    int pos = sofs[dlow] + atomicAdd(&cnt2[dlow], 1);
    ec[pos] = rec & 0xFFFFu;
  }
  __syncthreads();
  int base = sofs[t];
  for (int j = v; j < vp; j++) ec[base + j] = DUMMY_SRC;
}

// ---------------- bf16 MFMA GEMM, LDS-B dbuf + 2-deep named A prefetch ----------
// 256 thr = 4 waves; wave owns 32 rows; BM=128, grid=M/128. B staged once per
// block per K-step into double-buffered LDS. A prefetched TWO K-steps ahead
// into STATICALLY-NAMED register sets (rule #20). Both modes: 2-pass a*bh+a*bl
// (B split keeps weights 2^-17-exact; A at bf16 adds ~2^-9 — below the bf16
// table noise the output lands in anyway; gemm1's identical path validated at
// absmax 9.77e-4 in r17).
// AMODE 0: A fp32, converted to bf16 in regs (decode). AMODE 1: A bf16 plane.

#define GEMM_ISSUE_A(S, AR, AB)                                           \
  {                                                                       \
    _Pragma("unroll")                                                     \
    for (int mb = 0; mb < 2; mb++) {                                      \
      size_t base_ = (size_t)(r0 + mb * 16 + lr) * K + (S) * 32 + kg * 8; \
      if (AMODE == 0) {                                                   \
        const float* xp_ = (const float*)A0 + base_;                      \
        AR[mb * 2] = *(const f32x4*)xp_;                                  \
        AR[mb * 2 + 1] = *(const f32x4*)(xp_ + 4);                        \
      } else {                                                            \
        AB[mb] = *(const s16x8*)((const ushort*)A0 + base_);              \
      }                                                                   \
    }                                                                     \
  }

#define GEMM_STEP(S, AR, AB)                                              \
  {                                                                       \
    s16x8 ah[2];                                                          \
    if (AMODE == 0) {                                                     \
      _Pragma("unroll")                                                   \
      for (int mb = 0; mb < 2; mb++) {                                    \
        float xv[8] = {AR[mb*2].x, AR[mb*2].y, AR[mb*2].z, AR[mb*2].w,    \
                       AR[mb*2+1].x, AR[mb*2+1].y, AR[mb*2+1].z,          \
                       AR[mb*2+1].w};                                     \
        union { ushort u[8]; s16x8 v; } H_;                               \
        _Pragma("unroll")                                                 \
        for (int e = 0; e < 8; e++) H_.u[e] = f2bf(xv[e]);                \
        ah[mb] = H_.v;                                                    \
      }                                                                   \
    } else {                                                              \
      ah[0] = AB[0];                                                      \
      ah[1] = AB[1];                                                      \
    }                                                                     \
    if ((S) + 2 < nks) GEMM_ISSUE_A((S) + 2, AR, AB);                     \
    const bool more_ = ((S) + 1 < nks);                                   \
    if (more_) issueB((S) + 1);                                           \
    _Pragma("unroll")                                                     \
    for (int nb = 0; nb < 8; nb++) {                                      \
      s16x8 bh = *(const s16x8*)&Bs[buf][nb * 512 + l * 8];               \
      s16x8 bl = *(const s16x8*)&Bs[buf][4096 + nb * 512 + l * 8];        \
      _Pragma("unroll")                                                   \
      for (int mb = 0; mb < 2; mb++) {                                    \
        acc[mb][nb] = __builtin_amdgcn_mfma_f32_16x16x32_bf16(            \
            ah[mb], bh, acc[mb][nb], 0, 0, 0);                            \
        acc[mb][nb] = __builtin_amdgcn_mfma_f32_16x16x32_bf16(            \
            ah[mb], bl, acc[mb][nb], 0, 0, 0);                            \
      }                                                                   \
    }                                                                     \
    if (more_) {                                                          \
      writeB(buf ^ 1);                                                    \
      __syncthreads();                                                    \
      buf ^= 1;                                                           \
    }                                                                     \
  }

template <int AMODE>
__global__ __launch_bounds__(256) void k_gemm(const void* __restrict__ A0,
                                              const ushort* __restrict__ Whi,
                                              const ushort* __restrict__ Wlo,
                                              const float* __restrict__ bias,
                                              const float* __restrict__ scale,
                                              ushort* __restrict__ Y, int K) {
  __shared__ ushort Bs[2][8192];  // [buf][hi 4096 | lo 4096] = 32 KB
  const int t = threadIdx.x;
  const int w = t >> 6;
  const int l = t & 63;
  const int lr = l & 15;
  const int kg = l >> 4;
  const int r0 = blockIdx.x * 128 + w * 32;
  const int nks = K >> 5;  // 8 (decode) or 4 — always even

  f32x4 acc[2][8];
#pragma unroll
  for (int mb = 0; mb < 2; mb++)
#pragma unroll
    for (int nb = 0; nb < 8; nb++) acc[mb][nb] = (f32x4)0.f;

  // statically-named 2-deep A prefetch sets (constant indices after unroll)
  f32x4 arA[4], arB[4];
  s16x8 abA[2], abB[2];
  s16x8 bh0, bh1, bl0, bl1;

  auto issueB = [&](int s) {
    const ushort* ph = Whi + (size_t)s * 4096 + t * 16;
    const ushort* pl = Wlo + (size_t)s * 4096 + t * 16;
    bh0 = *(const s16x8*)ph;
    bh1 = *(const s16x8*)(ph + 8);
    bl0 = *(const s16x8*)pl;
    bl1 = *(const s16x8*)(pl + 8);
  };
  auto writeB = [&](int buf) {
    *(s16x8*)&Bs[buf][t * 16] = bh0;
    *(s16x8*)&Bs[buf][t * 16 + 8] = bh1;
    *(s16x8*)&Bs[buf][4096 + t * 16] = bl0;
    *(s16x8*)&Bs[buf][4096 + t * 16 + 8] = bl1;
  };

  GEMM_ISSUE_A(0, arA, abA);
  issueB(0);
  writeB(0);
  GEMM_ISSUE_A(1, arB, abB);  // nks >= 2 always
  __syncthreads();

  int buf = 0;
  for (int s = 0; s < nks; s += 2) {
    GEMM_STEP(s, arA, abA);
    GEMM_STEP(s + 1, arB, abB);
  }

  float dvr[2][4];
#pragma unroll
  for (int mb = 0; mb < 2; mb++)
#pragma unroll
    for (int r = 0; r < 4; r++)
      dvr[mb][r] = scale ? scale[r0 + mb * 16 + kg * 4 + r] : 1.f;

#pragma unroll
  for (int nb = 0; nb < 8; nb++) {
    int col = nb * 16 + lr;
    float bv = bias ? bias[col] : 0.f;
#pragma unroll
    for (int mb = 0; mb < 2; mb++)
#pragma unroll
      for (int r = 0; r < 4; r++) {
        size_t row = (size_t)(r0 + mb * 16 + kg * 4 + r);
        Y[row * FD + col] = f2bf((acc[mb][nb][r] + bv) * dvr[mb][r]);
      }
  }
}

// ---------------- GCN aggregation: wave-per-node, UNIFORM 8-deep pipeline ------
// (round-11/12/17 proven) Table t = dinv*h, bf16 [NN+1][128] (row NN = zeros).
// out[d] = relu( dinv[d]*(sum_e t[src_e] + t[d]) + b )
// EMIT=0: write SINGLE bf16 plane. EMIT=1: fused segment-max pooling.

template <int EMIT>
__global__ __launch_bounds__(256) void k_agg(const ushort* __restrict__ h16,
                                             const uint* __restrict__ ec,
                                             const int* __restrict__ offs,
                                             const int* __restrict__ hist,
                                             const float* __restrict__ dinv,
                                             const float* __restrict__ bias,
                                             ushort* __restrict__ yout,
                                             float* __restrict__ pooled) {
  __shared__ int pmax[128];
  const int t = threadIdx.x;
  if (EMIT == 1) {
    if (t < 128) pmax[t] = 0;
    __syncthreads();
  }
  const int n = blockIdx.x * 4 + (t >> 6);
  const int l = t & 63;
  const int half = l >> 5;
  const int dl = (l & 31) * 4;

  const int cnt_p = (hist[n] + 15) & ~15;  // padded count
  const uint* ep = ec + offs[n];

  float a0 = 0.f, a1 = 0.f, a2 = 0.f, a3 = 0.f;
  float b0 = 0.f, b1 = 0.f, b2 = 0.f, b3 = 0.f;
  for (int i = half; i < cnt_p; i += 16) {
    uint s0 = ep[i];
    uint s1 = ep[i + 2];
    uint s2 = ep[i + 4];
    uint s3 = ep[i + 6];
    uint s4 = ep[i + 8];
    uint s5 = ep[i + 10];
    uint s6 = ep[i + 12];
    uint s7 = ep[i + 14];
    ushort4 v0 = *(const ushort4*)(h16 + ((size_t)s0 << 7) + dl);
    ushort4 v1 = *(const ushort4*)(h16 + ((size_t)s1 << 7) + dl);
    ushort4 v2 = *(const ushort4*)(h16 + ((size_t)s2 << 7) + dl);
    ushort4 v3 = *(const ushort4*)(h16 + ((size_t)s3 << 7) + dl);
    ushort4 v4 = *(const ushort4*)(h16 + ((size_t)s4 << 7) + dl);
    ushort4 v5 = *(const ushort4*)(h16 + ((size_t)s5 << 7) + dl);
    ushort4 v6 = *(const ushort4*)(h16 + ((size_t)s6 << 7) + dl);
    ushort4 v7 = *(const ushort4*)(h16 + ((size_t)s7 << 7) + dl);
    a0 += bf2f(v0.x); a1 += bf2f(v0.y); a2 += bf2f(v0.z); a3 += bf2f(v0.w);
    b0 += bf2f(v1.x); b1 += bf2f(v1.y); b2 += bf2f(v1.z); b3 += bf2f(v1.w);
    a0 += bf2f(v2.x); a1 += bf2f(v2.y); a2 += bf2f(v2.z); a3 += bf2f(v2.w);
    b0 += bf2f(v3.x); b1 += bf2f(v3.y); b2 += bf2f(v3.z); b3 += bf2f(v3.w);
    a0 += bf2f(v4.x); a1 += bf2f(v4.y); a2 += bf2f(v4.z); a3 += bf2f(v4.w);
    b0 += bf2f(v5.x); b1 += bf2f(v5.y); b2 += bf2f(v5.z); b3 += bf2f(v5.w);
    a0 += bf2f(v6.x); a1 += bf2f(v6.y); a2 += bf2f(v6.z); a3 += bf2f(v6.w);
    b0 += bf2f(v7.x); b1 += bf2f(v7.y); b2 += bf2f(v7.z); b3 += bf2f(v7.w);
  }
  a0 += b0; a1 += b1; a2 += b2; a3 += b3;
  a0 += __shfl_xor(a0, 32);
  a1 += __shfl_xor(a1, 32);
  a2 += __shfl_xor(a2, 32);
  a3 += __shfl_xor(a3, 32);

  if (l < 32) {
    float dv = dinv[n];
    ushort4 vs = *(const ushort4*)(h16 + ((size_t)n << 7) + dl);  // t[d]
    float4 bb = *(const float4*)(bias + dl);
    float o0 = fmaxf(fmaf(dv, a0 + bf2f(vs.x), bb.x), 0.f);
    float o1 = fmaxf(fmaf(dv, a1 + bf2f(vs.y), bb.y), 0.f);
    float o2 = fmaxf(fmaf(dv, a2 + bf2f(vs.z), bb.z), 0.f);
    float o3 = fmaxf(fmaf(dv, a3 + bf2f(vs.w), bb.w), 0.f);
    if (EMIT == 0) {
      ushort4 hi;
      hi.x = f2bf(o0);
      hi.y = f2bf(o1);
      hi.z = f2bf(o2);
      hi.w = f2bf(o3);
      *(ushort4*)(yout + (size_t)n * FD + dl) = hi;
    } else {
      // relu>=0: int-compare == float-compare for non-negative floats
      atomicMax(&pmax[dl + 0], __float_as_int(o0));
      atomicMax(&pmax[dl + 1], __float_as_int(o1));
      atomicMax(&pmax[dl + 2], __float_as_int(o2));
      atomicMax(&pmax[dl + 3], __float_as_int(o3));
    }
  }
  if (EMIT == 1) {
    __syncthreads();
    if (t < 128) {
      int gr = blockIdx.x >> 6;  // 64 blocks (256 nodes) per graph
      atomicMax((int*)pooled + gr * FD + t, pmax[t]);
    }
  }
}

// ---------------- MLP head ----------------

__global__ __launch_bounds__(128) void k_mlp(const float* __restrict__ pooled,
                                             const float* __restrict__ Wp1,
                                             const float* __restrict__ bp1,
                                             const float* __restrict__ Wp2,
                                             const float* __restrict__ bp2,
                                             float* __restrict__ out) {
  __shared__ float row[128];
  __shared__ float red[128];
  int g = blockIdx.x, t = threadIdx.x;
  row[t] = pooled[g * FD + t];
  __syncthreads();
  float acc = bp1[t];
#pragma unroll 8
  for (int k = 0; k < 128; k++) acc = fmaf(row[k], Wp1[k * FD + t], acc);
  acc = fmaxf(acc, 0.f);
  red[t] = acc * Wp2[t];
  __syncthreads();
  for (int st = 64; st > 0; st >>= 1) {
    if (t < st) red[t] += red[t + st];
    __syncthreads();
  }
  if (t == 0) out[g] = red[0] + bp2[0];
}

// ---------------- launch ----------------

extern "C" void kernel_launch(void* const* d_in, const int* in_sizes, int n_in,
                              void* d_out, int out_size, void* d_ws, size_t ws_size,
                              hipStream_t stream) {
  (void)in_sizes; (void)n_in; (void)out_size; (void)ws_size;

  const float* adj  = (const float*)d_in[0];
  const int*   edges= (const int*)d_in[1];
  const float* Wdec = (const float*)d_in[3];
  const float* bdec = (const float*)d_in[4];
  const float* Wc1  = (const float*)d_in[5];
  const float* bc1  = (const float*)d_in[6];
  const float* Wc2  = (const float*)d_in[7];
  const float* bc2  = (const float*)d_in[8];
  const float* Wp1  = (const float*)d_in[9];
  const float* bp1  = (const float*)d_in[10];
  const float* Wp2  = (const float*)d_in[11];
  const float* bp2  = (const float*)d_in[12];
  float* out = (float*)d_out;

  char* ws = (char*)d_ws;
  size_t off = 0;
  auto alloc = [&](size_t bytes) -> void* {
    void* p = ws + off;
    off += (bytes + 255) & ~(size_t)255;
    return p;
  };
  ushort* h16  = (ushort*)alloc((size_t)(NN + 1) * FD * 2);  // +1 zero row
  ushort* x1   = (ushort*)alloc((size_t)NN * FD * 2);        // single bf16 plane
  // pooled | gbin contiguous -> single memset
  float*  pooled = (float*)alloc((size_t)NGRAPH * FD * 4);
  int*    gbin = (int*)alloc(256 * 4);
  int*    hist = (int*)alloc((size_t)NN * 4);
  int*    offs = (int*)alloc((size_t)NN * 4);
  uint*   ec   = (uint*)alloc((size_t)256 * BCAPP * 4);   // 8.7 MB fixed windows
  uint*   binbuf = (uint*)alloc((size_t)256 * BCAP * 4);  // 4.7 MB bucket bins
  float*  dinv = (float*)alloc((size_t)NN * 4);
  float*  bfused = (float*)alloc(FD * 4);
  ushort* wfh = (ushort*)alloc((size_t)KDEC * FD * 2);
  ushort* wfl = (ushort*)alloc((size_t)KDEC * FD * 2);
  ushort* w2h = (ushort*)alloc((size_t)FD * FD * 2);
  ushort* w2l = (ushort*)alloc((size_t)FD * FD * 2);

  hipMemsetAsync(pooled, 0, (size_t)NGRAPH * FD * 4 + 256 * 4, stream);
  hipMemsetAsync(h16 + (size_t)NN * FD, 0, FD * 2, stream);  // zero row (dummy target)

  // binning + Wfused compute&split + Wc2 split (parallel block roles)
  k_histbin<<<304, 1024, 0, stream>>>(edges, binbuf, gbin, Wdec, Wc1, bdec,
                                      bfused, wfh, wfl, Wc2, w2h, w2l);
  // bucket-local CSR: count -> local scan -> offs/hist/dinv -> scatter -> pad
  k_misc<<<256, 256, 0, stream>>>(binbuf, gbin, hist, offs, dinv, ec);

  // t1 = dinv * (adj @ Wfused + bfused) -> bf16 table (bf16-A 2-pass)
  k_gemm<0><<<NN / 128, 256, 0, stream>>>(adj, wfh, wfl, bfused, dinv, h16, KDEC);

  // x1 = relu(dinv*(sum t1 + t1_self) + bc1) -> single bf16 plane
  k_agg<0><<<NN / 4, 256, 0, stream>>>(h16, ec, offs, hist, dinv, bc1, x1, nullptr);

  // t2 = dinv * (x1 @ Wc2) -> bf16 table (bf16-A 2-pass)
  k_gemm<1><<<NN / 128, 256, 0, stream>>>(x1, w2h, w2l, nullptr, dinv, h16, FD);

  // pooled = segmax(relu(dinv*(sum t2 + t2_self) + bc2)) fused
  k_agg<1><<<NN / 4, 256, 0, stream>>>(h16, ec, offs, hist, dinv, bc2, nullptr, pooled);

  // MLP head
  k_mlp<<<NGRAPH, 128, 0, stream>>>(pooled, Wp1, bp1, Wp2, bp2, out);
}